// Round 11
// baseline (180.842 us; speedup 1.0000x reference)
//
#include <hip/hip_runtime.h>
#include <hip/hip_bf16.h>
#include <stdint.h>

// ---------------------------------------------------------------------------
// SelfAttn: B=4, W=H=64, C=256, C2=128, N=W*H=4096.
// pq = raw q buffer viewed [128,4096]  (Q_rows[n,c] = q_flat[c*4096+n])
// pv = raw v buffer viewed [256,4096]
// energy = Qrm @ Krm^T (K=128), softmax over keys (fixed ref m=0),
// O[n,c] = sum_m P[n,m] V[m,c];  final[b,c*4096+n] = gamma*O/l + x.
//
// R10 post-mortem: attn 72us on model; non-attn ~103us dominated by
// per-dispatch overhead (~20us/kernel; evidence: removing trivial conv_x in
// R1->R3 cut 46us). R11: fuse merge_out INTO attn (4 -> 3 kernels): blocks
// own 32 queries x ALL keys (no ks split -> exact l in-block), epilogue does
// l-reduce + gamma*O/l + x + transpose + final store. Opart/Lpart deleted.
// ---------------------------------------------------------------------------

typedef __attribute__((ext_vector_type(8)))  short short8;   // 8 x bf16
typedef __attribute__((ext_vector_type(4)))  float f32x4;
typedef __attribute__((ext_vector_type(16))) float f32x16;
typedef __attribute__((ext_vector_type(4)))  unsigned short u16x4;

#define MFMA16 __builtin_amdgcn_mfma_f32_16x16x32_bf16
#define MFMA32 __builtin_amdgcn_mfma_f32_32x32x16_bf16

__device__ __forceinline__ unsigned short f2bf(float f) {
    union { float f; uint32_t u; } v; v.f = f;
    return (unsigned short)((v.u + 0x8000u) >> 16);    // round-half-up
}
// packed f32x2 -> bf16x2 (v_cvt_pk_bf16_f32, RNE)
__device__ __forceinline__ uint32_t pkbf(float a, float b) {
    union { __hip_bfloat162 h; uint32_t u; } v;
    v.h = __float22bfloat162_rn(float2{a, b});
    return v.u;
}

// --- K1: Wt[512][256] bf16 (transposed, fused qkv) + bias[512] f32 ---------
__global__ void prep_w(const float* __restrict__ Wq, const float* __restrict__ bq,
                       const float* __restrict__ Wk, const float* __restrict__ bk,
                       const float* __restrict__ Wv, const float* __restrict__ bv,
                       unsigned short* __restrict__ Wt, float* __restrict__ bias) {
    int g = blockIdx.x * 256 + threadIdx.x;
    int c = g & 255, d = g >> 8;
    float val;
    if (d < 128)      val = Wq[c * 128 + d];
    else if (d < 256) val = Wk[c * 128 + (d - 128)];
    else              val = Wv[c * 256 + (d - 256)];
    Wt[d * 256 + c] = f2bf(val);
    if (g < 512) {
        float bb;
        if (g < 128)      bb = bq[g];
        else if (g < 256) bb = bk[g - 128];
        else              bb = bv[g - 256];
        bias[g] = bb;
    }
}

// --- K2: fused QKV projection. 512 uniform blocks (unchanged from R10):
//   [0,128)   Q-kind -> Qrm [n][128] tiles
//   [128,256) K-kind -> Kp[c-chunk(8)][m(4096)][k(16)] packed
//   [256,512) V-kind -> Vp[m-chunk(256)][c(256)][k(16)] packed
__global__ __launch_bounds__(256) void proj(
        const float* __restrict__ x, const unsigned short* __restrict__ Wt,
        const float* __restrict__ bias,
        unsigned short* __restrict__ Qrm, unsigned short* __restrict__ Kp,
        unsigned short* __restrict__ Vp) {
    __shared__ unsigned short T[128 * 136];
    int bid = blockIdx.x;
    int tid = threadIdx.x;
    int wave = tid >> 6, lane = tid & 63;
    int l16 = lane & 15, quad = lane >> 4;

    int kind, b, a, vh = 0;
    if (bid < 256) { kind = bid >> 7; int s = bid & 127; b = s >> 5; a = s & 31; }
    else           { kind = 2; int s = bid - 256; vh = s >> 7; b = (s >> 5) & 3; a = s & 31; }

    short8 af[2][8];
    #pragma unroll
    for (int g = 0; g < 2; ++g) {
        int p_local = wave * 32 + g * 16 + l16;
        int pix = (kind == 2) ? (b * 4096 + a * 128 + p_local)
                              : (b * 4096 + a + 32 * p_local);
        const float* xr = x + (size_t)pix * 256;
        #pragma unroll
        for (int kk = 0; kk < 8; ++kk) {
            f32x4 u0 = *(const f32x4*)(xr + kk * 32 + quad * 8);
            f32x4 u1 = *(const f32x4*)(xr + kk * 32 + quad * 8 + 4);
            union { short8 s; uint32_t u[4]; } h;
            h.u[0] = pkbf(u0[0], u0[1]); h.u[1] = pkbf(u0[2], u0[3]);
            h.u[2] = pkbf(u1[0], u1[1]); h.u[3] = pkbf(u1[2], u1[3]);
            af[g][kk] = h.s;
        }
    }

    if (kind < 2) {
        int dbase = kind * 128;
        #pragma unroll 1
        for (int dt = 0; dt < 8; ++dt) {
            int d = dbase + dt * 16 + l16;
            float bval = bias[d];
            f32x4 acc0 = {0.f,0.f,0.f,0.f}, acc1 = {0.f,0.f,0.f,0.f};
            #pragma unroll
            for (int kk = 0; kk < 8; ++kk) {
                short8 wrow = *(const short8*)(Wt + d * 256 + kk * 32 + quad * 8);
                acc0 = MFMA16(af[0][kk], wrow, acc0, 0, 0, 0);
                acc1 = MFMA16(af[1][kk], wrow, acc1, 0, 0, 0);
            }
            #pragma unroll
            for (int g = 0; g < 2; ++g) {
                f32x4 acc = g ? acc1 : acc0;
                union { u16x4 v; uint32_t u[2]; } pk;
                pk.u[0] = pkbf(acc[0] + bval, acc[1] + bval);
                pk.u[1] = pkbf(acc[2] + bval, acc[3] + bval);
                *(u16x4*)(T + (dt * 16 + l16) * 136 + wave * 32 + g * 16 + quad * 4) = pk.v;
            }
        }
        __syncthreads();
        if (kind == 0) {
            unsigned short* ob = Qrm + (b << 19) + a * 128 * 128;
            #pragma unroll
            for (int it = 0; it < 8; ++it) {
                int ci = it * 256 + tid;
                int row = ci >> 4, cj = ci & 15;
                *(short8*)(ob + row * 128 + cj * 8) = *(const short8*)(T + row * 136 + cj * 8);
            }
        } else {
            unsigned short* kb = Kp + (b << 19);
            #pragma unroll
            for (int it = 0; it < 8; ++it) {
                int ci = it * 256 + tid;
                int row = ci >> 4, cj = ci & 15;
                *(short8*)(kb + (cj >> 1) * 65536 + (a * 128 + row) * 16 + (cj & 1) * 8)
                    = *(const short8*)(T + row * 136 + cj * 8);
            }
        }
    } else {
        #pragma unroll 1
        for (int dt = 0; dt < 8; ++dt) {
            int d = 256 + vh * 128 + dt * 16 + l16;
            f32x4 acc0 = {0.f,0.f,0.f,0.f}, acc1 = {0.f,0.f,0.f,0.f};
            #pragma unroll
            for (int kk = 0; kk < 8; ++kk) {
                short8 wrow = *(const short8*)(Wt + d * 256 + kk * 32 + quad * 8);
                acc0 = MFMA16(wrow, af[0][kk], acc0, 0, 0, 0);   // A=W, B=x -> D^T
                acc1 = MFMA16(wrow, af[1][kk], acc1, 0, 0, 0);
            }
            int dvl = dt * 16 + quad * 4;
            f32x4 bv4 = *(const f32x4*)(bias + 256 + vh * 128 + dvl);
            #pragma unroll
            for (int g = 0; g < 2; ++g) {
                f32x4 acc = g ? acc1 : acc0;
                union { u16x4 v; uint32_t u[2]; } pk;
                pk.u[0] = pkbf(acc[0] + bv4[0], acc[1] + bv4[1]);
                pk.u[1] = pkbf(acc[2] + bv4[2], acc[3] + bv4[3]);
                int p_local = wave * 32 + g * 16 + l16;
                *(u16x4*)(T + p_local * 136 + dvl) = pk.v;
            }
        }
        __syncthreads();
        unsigned short* vb = Vp + (b << 20);
        #pragma unroll
        for (int it = 0; it < 8; ++it) {
            int cid = it * 256 + tid;
            int c_local = cid >> 8, w = cid & 255;
            int p_local = c_local * 16 + (w >> 4);
            int chunk = (w >> 4) * 16 + vh * 8 + ((w & 15) >> 1);
            *(short8*)(vb + chunk * 4096 + (a * 8 + c_local) * 16 + (w & 1) * 8)
                = *(const short8*)(T + p_local * 136 + (w & 15) * 8);
        }
    }
}

// --- K3: fused flash attention + output epilogue ---------------------------
// grid 512 = 128 qtiles(32 q) x 4 b; 256 threads. kt = 128-key tiles x 32.
// Wave w: QK rows m in [32w,32w+32) (8 MFMA32), softmax in-lane, Ps exchange
// (dbuf, 1 barrier/kt), PV over ctiles {2w,2w+1} (16 MFMA32, O=32 AGPR).
// Epilogue: cross-wave l-reduce, gamma*O/l via LDS transpose, +x, final out.
__global__ __launch_bounds__(256, 2) void attn(
        const unsigned short* __restrict__ Qrm, const unsigned short* __restrict__ Kp,
        const unsigned short* __restrict__ Vp, const float* __restrict__ x,
        const float* __restrict__ gamma, float* __restrict__ out) {
    __shared__ __align__(16) char smem[256 * 36 * 4];  // 36,864 B union
    __shared__ float Ls[4][32];
    __shared__ float lwv[32];
    unsigned short* Ps = (unsigned short*)smem;        // [2][32][136] u16 (17,408 B)
    float* Os = (float*)smem;                          // [256 c][36] f32

    int bid = blockIdx.x;
    int b = bid & 3, qt = bid >> 2;                    // bid%8 spreads b over XCDs
    int tid = threadIdx.x, wave = tid >> 6, lane = tid & 63;
    int l32 = lane & 31, half = lane >> 5;

    const unsigned short* Qb = Qrm + (b << 19);
    const unsigned short* Kb = Kp + (b << 19);
    const unsigned short* Vb = Vp + (b << 20);

    int n0 = qt * 32;
    float gm = gamma[0];

    short8 qf[8];                                      // B=Q: lane n-col = l32
    {
        const unsigned short* qrow = Qb + (n0 + l32) * 128 + half * 8;
        #pragma unroll
        for (int kk = 0; kk < 8; ++kk) qf[kk] = *(const short8*)(qrow + kk * 16);
    }

    f32x16 O[2];                                       // 2 ctiles -> 32 AGPR
    #pragma unroll
    for (int j = 0; j < 2; ++j)
        #pragma unroll
        for (int r = 0; r < 16; ++r) O[j][r] = 0.f;
    float l_run = 0.f;

    // tile-0 fragments (coalesced packed loads)
    short8 kf[8];
    {
        int m0 = (wave * 32 + l32) * 16 + half * 8;
        #pragma unroll
        for (int kk = 0; kk < 8; ++kk)
            kf[kk] = *(const short8*)(Kb + kk * 65536 + m0);
    }
    short8 vfrag[2][8];
    #pragma unroll
    for (int c2 = 0; c2 < 2; ++c2)
        #pragma unroll
        for (int k2 = 0; k2 < 8; ++k2)
            vfrag[c2][k2] = *(const short8*)(Vb + k2 * 4096
                              + ((wave * 2 + c2) * 32 + l32) * 16 + half * 8);

    #pragma unroll 1
    for (int kt = 0; kt < 32; ++kt) {
        unsigned short* Pb = Ps + (kt & 1) * (32 * 136);

        // 1. S^T[m][n]: A=kf, B=qf; col n = l32, row m(within wave's 32) =
        //    (r&3)+8*(r>>2)+4*half.
        f32x16 S;
        #pragma unroll
        for (int r = 0; r < 16; ++r) S[r] = 0.f;
        #pragma unroll
        for (int kk = 0; kk < 8; ++kk) S = MFMA32(kf[kk], qf[kk], S, 0, 0, 0);

        // 2. fixed-ref softmax: p = exp(S); pack -> Ps[buf][q=l32][m]
        #pragma unroll
        for (int g = 0; g < 4; ++g) {
            float p0 = __expf(S[g * 4 + 0]), p1 = __expf(S[g * 4 + 1]);
            float p2 = __expf(S[g * 4 + 2]), p3 = __expf(S[g * 4 + 3]);
            l_run += (p0 + p1) + (p2 + p3);
            union { u16x4 v; uint32_t u[2]; } pk;
            pk.u[0] = pkbf(p0, p1); pk.u[1] = pkbf(p2, p3);
            // m = wave*32 + g*8 + half*4 + i
            *(u16x4*)(Pb + l32 * 136 + wave * 32 + g * 8 + half * 4) = pk.v;
        }

        __syncthreads();                               // 3. Ps[buf] ready

        if (kt < 31) {                                 // 4. kf prefetch
            int m1 = ((kt + 1) * 128 + wave * 32 + l32) * 16 + half * 8;
            #pragma unroll
            for (int kk = 0; kk < 8; ++kk)
                kf[kk] = *(const short8*)(Kb + kk * 65536 + m1);
        }

        // 5. PV: A = P rows q (l32), B = vfrag; 8 k-chunks of 16
        #pragma unroll
        for (int k2 = 0; k2 < 8; ++k2) {
            short8 pa = *(const short8*)(Pb + l32 * 136 + k2 * 16 + half * 8);
            O[0] = MFMA32(pa, vfrag[0][k2], O[0], 0, 0, 0);
            O[1] = MFMA32(pa, vfrag[1][k2], O[1], 0, 0, 0);
        }

        if (kt < 31) {                                 // 6. vfrag prefetch
            int ch1 = (kt + 1) * 8;
            #pragma unroll
            for (int c2 = 0; c2 < 2; ++c2)
                #pragma unroll
                for (int k2 = 0; k2 < 8; ++k2)
                    vfrag[c2][k2] = *(const short8*)(Vb + (ch1 + k2) * 4096
                                      + ((wave * 2 + c2) * 32 + l32) * 16 + half * 8);
        }
    }

    // ---- fused epilogue ----
    // cross-wave l reduction: lwv[q] = gamma / sum_m exp
    l_run += __shfl_xor(l_run, 32);
    if (half == 0) Ls[wave][l32] = l_run;
    __syncthreads();                                   // also: last PV reads done
    if (tid < 32)
        lwv[tid] = gm / (Ls[0][tid] + Ls[1][tid] + Ls[2][tid] + Ls[3][tid]);
    __syncthreads();

    // stage normalized O into Os[c][q] (pitch 36), rows q = g*8+half*4+i
    #pragma unroll
    for (int c2 = 0; c2 < 2; ++c2) {
        int c = (wave * 2 + c2) * 32 + l32;
        #pragma unroll
        for (int g = 0; g < 4; ++g) {
            f32x4 gv = *(const f32x4*)(lwv + g * 8 + half * 4);
            f32x4 ov;
            #pragma unroll
            for (int i = 0; i < 4; ++i) ov[i] = O[c2][g * 4 + i] * gv[i];
            *(f32x4*)(Os + c * 36 + g * 8 + half * 4) = ov;
        }
    }
    __syncthreads();

    // write out[b, c*4096 + n0+n] = Os + x, coalesced (8 n-quads x 32 c-groups)
    int n4 = tid & 7, cg = tid >> 3;
    #pragma unroll
    for (int it = 0; it < 8; ++it) {
        int c = it * 32 + cg;
        f32x4 ov = *(const f32x4*)(Os + c * 36 + n4 * 4);
        size_t idx = ((size_t)b << 20) + (size_t)c * 4096 + n0 + n4 * 4;
        f32x4 xv = *(const f32x4*)(x + idx);
        f32x4 rv;
        #pragma unroll
        for (int e = 0; e < 4; ++e) rv[e] = ov[e] + xv[e];
        *(f32x4*)(out + idx) = rv;
    }
}

// ---------------------------------------------------------------------------
extern "C" void kernel_launch(void* const* d_in, const int* in_sizes, int n_in,
                              void* d_out, int out_size, void* d_ws, size_t ws_size,
                              hipStream_t stream) {
    const float* x     = (const float*)d_in[0];
    const float* Wq    = (const float*)d_in[1];
    const float* bq    = (const float*)d_in[2];
    const float* Wk    = (const float*)d_in[3];
    const float* bk    = (const float*)d_in[4];
    const float* Wv    = (const float*)d_in[5];
    const float* bv    = (const float*)d_in[6];
    const float* gamma = (const float*)d_in[7];
    float* out = (float*)d_out;

    if (ws_size < 17041408u) return;   // need ~17 MB scratch

    char* ws = (char*)d_ws;
    unsigned short* Wt    = (unsigned short*)(ws);             //    262,144 B
    float*          bias  = (float*)        (ws +   262144);   //      2,048 B
    unsigned short* Qrm   = (unsigned short*)(ws +   264192);  //  4,194,304 B
    unsigned short* Kp    = (unsigned short*)(ws +  4458496);  //  4,194,304 B
    unsigned short* Vp    = (unsigned short*)(ws +  8652800);  //  8,388,608 B

    prep_w<<<512, 256, 0, stream>>>(Wq, bq, Wk, bk, Wv, bv, Wt, bias);
    proj  <<<512, 256, 0, stream>>>(x, Wt, bias, Qrm, Kp, Vp);
    attn  <<<512, 256, 0, stream>>>(Qrm, Kp, Vp, x, gamma, out);
}